// Round 12
// baseline (843.039 us; speedup 1.0000x reference)
//
#include <hip/hip_runtime.h>

#define SS 512
#define NPARTS 11
#define NB 4
#define FEAT (9*126*126)   // 142884

// ws layout (floats)
#define H1SZ (4*7*254*254)       // 1806448
#define H2SZ (4*FEAT)            // 571536
#define OFF_H1 0
#define OFF_H2 (OFF_H1 + H1SZ)
#define OFF_PART (OFF_H2 + H2SZ)      // [32][8][4] = 1024
#define OFF_THETA (OFF_PART + 1024)   // [4][66] = 264

// ---------------- conv1 (5x5, 4->7) + relu + maxpool2 ----------------
// No input LDS tile: 6x6 float4 window read DIRECTLY from global (vmcnt domain,
// L1-cached). Weights in LDS [tap][k][c] float4 broadcast (lgkmcnt domain).
// dy loop NOT unrolled -> body ~1.6KB, fits I-cache. 4 waves/SIMD.
__global__ __launch_bounds__(256, 4) void conv1_kernel(
    const float4* __restrict__ x4,
    const float* __restrict__ w,      // [7][4][5][5] original layout
    const float* __restrict__ bias,   // [7]
    float* __restrict__ h1) {
  __shared__ float4 wlds[175];        // [tap 25][k 7], float4 over c (2.8 KB)
  int tid = threadIdx.x;
  {
    float* wf = (float*)wlds;
    for (int i = tid; i < 700; i += 256) {
      int tap = i / 28, r = i % 28;
      int k = r >> 2, c = r & 3;
      int dy = tap / 5, dx = tap % 5;
      wf[i] = w[((k * 4 + c) * 5 + dy) * 5 + dx];
    }
  }
  __syncthreads();

  int b = blockIdx.y;
  int by = blockIdx.x >> 4, bx = blockIdx.x & 15;
  int ty = tid >> 4, tx = tid & 15;
  int py = by * 16 + ty, px = bx * 16 + tx;
  if (py >= 254 || px >= 254) return;   // after barrier: safe

  const float4* img = x4 + (size_t)b * 6144 * 512 + (size_t)(2 * py) * 512 + 2 * px;

  float acc[4][7];
#pragma unroll
  for (int p = 0; p < 4; p++)
#pragma unroll
    for (int k = 0; k < 7; k++) acc[p][k] = bias[k];

#pragma unroll 1
  for (int dy = 0; dy < 5; dy++) {
    const float4* r0 = img + dy * 512;
    const float4* r1 = r0 + 512;
    float4 a0[6], a1[6];
#pragma unroll
    for (int j = 0; j < 6; j++) { a0[j] = r0[j]; a1[j] = r1[j]; }
#pragma unroll
    for (int dx = 0; dx < 5; dx++) {
      float4 v00 = a0[dx], v01 = a0[dx + 1];
      float4 v10 = a1[dx], v11 = a1[dx + 1];
      const float4* wp = &wlds[(dy * 5 + dx) * 7];
#pragma unroll
      for (int k = 0; k < 7; k++) {
        float4 wv = wp[k];                 // uniform ds_read_b128 broadcast
        acc[0][k] += v00.x * wv.x + v00.y * wv.y + v00.z * wv.z + v00.w * wv.w;
        acc[1][k] += v01.x * wv.x + v01.y * wv.y + v01.z * wv.z + v01.w * wv.w;
        acc[2][k] += v10.x * wv.x + v10.y * wv.y + v10.z * wv.z + v10.w * wv.w;
        acc[3][k] += v11.x * wv.x + v11.y * wv.y + v11.z * wv.z + v11.w * wv.w;
      }
    }
  }

#pragma unroll
  for (int k = 0; k < 7; k++) {
    float m = fmaxf(fmaxf(acc[0][k], acc[1][k]), fmaxf(acc[2][k], acc[3][k]));
    h1[(((size_t)b * 7 + k) * 254 + py) * 254 + px] = fmaxf(m, 0.0f);
  }
}

// ---------------- conv2 (3x3, 7->9) + relu + maxpool2, LDS-tiled ----------------
__global__ __launch_bounds__(256) void conv2_kernel(
    const float* __restrict__ h1,     // [4][7][254][254]
    const float* __restrict__ w,      // [9][7][3][3]
    const float* __restrict__ bias,   // [9]
    float* __restrict__ h2) {
  __shared__ float tile[7 * 34 * 35];
  int tid = threadIdx.x;
  int b = blockIdx.y;
  int by = blockIdx.x >> 3, bx = blockIdx.x & 7;
  int y0 = by * 32, x0 = bx * 32;

  for (int i = tid; i < 7 * 34 * 34; i += 256) {
    int c = i / (34 * 34), rem = i % (34 * 34);
    int r = rem / 34, col = rem % 34;
    int gy = y0 + r, gx = x0 + col;
    float v = 0.f;
    if (gy < 254 && gx < 254)
      v = h1[(((size_t)b * 7 + c) * 254 + gy) * 254 + gx];
    tile[(c * 34 + r) * 35 + col] = v;
  }
  __syncthreads();

  int ty = tid >> 4, tx = tid & 15;
  float acc[4][9];
#pragma unroll
  for (int p = 0; p < 4; p++)
#pragma unroll
    for (int k = 0; k < 9; k++) acc[p][k] = bias[k];

  for (int c = 0; c < 7; c++) {
#pragma unroll
    for (int dy = 0; dy < 3; dy++) {
      const float* r0 = &tile[(c * 34 + 2 * ty + dy) * 35 + 2 * tx];
      const float* r1 = r0 + 35;
      float a0[4], a1[4];
#pragma unroll
      for (int j = 0; j < 4; j++) { a0[j] = r0[j]; a1[j] = r1[j]; }
#pragma unroll
      for (int dx = 0; dx < 3; dx++) {
#pragma unroll
        for (int k = 0; k < 9; k++) {
          float wv = w[k * 63 + c * 9 + dy * 3 + dx];  // uniform -> scalar load
          acc[0][k] += a0[dx] * wv;
          acc[1][k] += a0[dx + 1] * wv;
          acc[2][k] += a1[dx] * wv;
          acc[3][k] += a1[dx + 1] * wv;
        }
      }
    }
  }

  int py = by * 16 + ty, px = bx * 16 + tx;
  if (py < 126 && px < 126) {
#pragma unroll
    for (int k = 0; k < 9; k++) {
      float m = fmaxf(fmaxf(acc[0][k], acc[1][k]), fmaxf(acc[2][k], acc[3][k]));
      h2[(((size_t)b * 9 + k) * 126 + py) * 126 + px] = fmaxf(m, 0.0f);
    }
  }
}

// ---------------- fc1 split-K partials ----------------
__global__ __launch_bounds__(256) void fc1_kernel(
    const float* __restrict__ h2,    // [4][FEAT]
    const float* __restrict__ w,     // [32][FEAT]
    float* __restrict__ partials) {
  int j = blockIdx.x;
  int s = blockIdx.y;
  int tid = threadIdx.x;
  const int CH = (FEAT + 7) / 8;
  int f0 = s * CH;
  int f1 = f0 + CH; if (f1 > FEAT) f1 = FEAT;
  float a0 = 0.f, a1 = 0.f, a2 = 0.f, a3 = 0.f;
  const float* wj = w + (size_t)j * FEAT;
  for (int f = f0 + tid; f < f1; f += 256) {
    float wv = wj[f];
    a0 += wv * h2[f];
    a1 += wv * h2[FEAT + f];
    a2 += wv * h2[2 * FEAT + f];
    a3 += wv * h2[3 * FEAT + f];
  }
  __shared__ float4 red[256];
  red[tid] = make_float4(a0, a1, a2, a3);
  __syncthreads();
  for (int off = 128; off > 0; off >>= 1) {
    if (tid < off) {
      float4 o = red[tid + off];
      red[tid].x += o.x; red[tid].y += o.y; red[tid].z += o.z; red[tid].w += o.w;
    }
    __syncthreads();
  }
  if (tid == 0) {
    float4 r = red[0];
    float* p = partials + ((size_t)j * 8 + s) * 4;
    p[0] = r.x; p[1] = r.y; p[2] = r.z; p[3] = r.w;
  }
}

// ---------------- head: finish fc1, fc2, fc3, side outputs ----------------
__global__ __launch_bounds__(256) void head_kernel(
    const float* __restrict__ partials,
    const float* __restrict__ b1,     // [32]
    const float* __restrict__ w2,     // [33][32]
    const float* __restrict__ b2,     // [33]
    const float* __restrict__ w3,     // [66][33]
    const float* __restrict__ b3,     // [66]
    float* __restrict__ theta_out,    // [4][66]
    float* __restrict__ out_tail) {   // close_to_eye(176) + translations(88)
  __shared__ float h32[128];
  __shared__ float h33[132];
  __shared__ float th[264];
  int tid = threadIdx.x;
  for (int t = tid; t < 128; t += 256) {
    int b = t >> 5, j = t & 31;
    float sacc = b1[j];
    for (int k = 0; k < 8; k++) sacc += partials[((size_t)j * 8 + k) * 4 + b];
    h32[b * 32 + j] = fmaxf(sacc, 0.0f);
  }
  __syncthreads();
  for (int t = tid; t < 132; t += 256) {
    int b = t / 33, j2 = t % 33;
    float sacc = b2[j2];
    for (int j = 0; j < 32; j++) sacc += h32[b * 32 + j] * w2[j2 * 32 + j];
    h33[b * 33 + j2] = fmaxf(sacc, 0.0f);
  }
  __syncthreads();
  for (int t = tid; t < 264; t += 256) {
    int b = t / 66, u = t % 66;
    float sacc = b3[u];
    for (int j2 = 0; j2 < 33; j2++) sacc += h33[b * 33 + j2] * w3[u * 33 + j2];
    th[t] = sacc;
    theta_out[t] = sacc;
  }
  __syncthreads();
  for (int t = tid; t < 176; t += 256) {
    int b = t / 44, r = t % 44, p = r / 4, ik = r % 4;
    int i = ik >> 1, k = ik & 1;
    const float* T = &th[b * 66 + p * 6];
    out_tail[t] = T[i * 3 + 0] * T[k * 3 + 0] + T[i * 3 + 1] * T[k * 3 + 1];
  }
  for (int t = tid; t < 88; t += 256) {
    int b = t / 22, r = t % 22, p = r / 2, i = r % 2;
    out_tail[176 + t] = th[b * 66 + p * 6 + i * 3 + 2];
  }
}

// ---------------- warp + alpha composite, depth-2 cross-part pipeline ----------------
__global__ __launch_bounds__(256) void warp_kernel(
    const float4* __restrict__ x4,
    const float* __restrict__ theta,  // [4][66]
    float* __restrict__ out) {
  int bid = blockIdx.x;
  int swz = (bid & 7) * 512 + (bid >> 3);   // 4096 blocks, XCD-chunked
  int b = swz >> 10;
  int t = swz & 1023;
  int ty = t >> 5, tx = t & 31;             // 32x32 tiles of 16x16
  int tid = threadIdx.x;
  int wv = tid >> 6, l = tid & 63;
  int y = ty * 16 + wv * 4 + (l >> 4);
  int x = tx * 16 + (l & 15);

  __shared__ float th[66];
  if (tid < 66) th[tid] = theta[b * 66 + tid];
  __syncthreads();

  const float4* img0 = x4 + (size_t)b * 6144 * 512 + 262144;  // part 0 chunk
  float fx = (float)x, fy = (float)y;
  const float cn = (1.0f / 512.0f) - 1.0f;

  float4 v00, v01, v10, v11;
  float wx, wy;
  {
    float T0 = th[0], T1 = th[1], T2 = th[2];
    float T3 = th[3], T4 = th[4], T5 = th[5];
    float Cx = 256.0f * ((T0 + T1) * cn + T2) + 255.5f;
    float Cy = 256.0f * ((T3 + T4) * cn + T5) + 255.5f;
    float ix = fmaf(T0, fx, fmaf(T1, fy, Cx));
    float iy = fmaf(T3, fx, fmaf(T4, fy, Cy));
    float xf = floorf(ix), yf = floorf(iy);
    wx = ix - xf; wy = iy - yf;
    int x0i = min(max((int)xf, 0), 511);
    int x1i = min(max((int)xf + 1, 0), 511);
    int y0i = min(max((int)yf, 0), 511);
    int y1i = min(max((int)yf + 1, 0), 511);
    int off00 = y0i * 512 + x0i;
    int dxs = x1i - x0i, dys = (y1i - y0i) * 512;
    v00 = img0[off00];
    v01 = img0[off00 + dxs];
    v10 = img0[off00 + dys];
    v11 = img0[off00 + dys + dxs];
  }

  float4 stack = make_float4(0.f, 0.f, 0.f, 0.f);
#pragma unroll 1
  for (int i = 0; i < NPARTS; i++) {
    float cwx = wx, cwy = wy;
    float4 c00 = v00, c01 = v01, c10 = v10, c11 = v11;
    if (i + 1 < NPARTS) {
      float T0 = th[(i + 1) * 6 + 0], T1 = th[(i + 1) * 6 + 1], T2 = th[(i + 1) * 6 + 2];
      float T3 = th[(i + 1) * 6 + 3], T4 = th[(i + 1) * 6 + 4], T5 = th[(i + 1) * 6 + 5];
      float Cx = 256.0f * ((T0 + T1) * cn + T2) + 255.5f;
      float Cy = 256.0f * ((T3 + T4) * cn + T5) + 255.5f;
      float ix = fmaf(T0, fx, fmaf(T1, fy, Cx));
      float iy = fmaf(T3, fx, fmaf(T4, fy, Cy));
      float xf = floorf(ix), yf = floorf(iy);
      wx = ix - xf; wy = iy - yf;
      int x0i = min(max((int)xf, 0), 511);
      int x1i = min(max((int)xf + 1, 0), 511);
      int y0i = min(max((int)yf, 0), 511);
      int y1i = min(max((int)yf + 1, 0), 511);
      int off00 = y0i * 512 + x0i;
      int dxs = x1i - x0i, dys = (y1i - y0i) * 512;
      const float4* img = img0 + (size_t)(i + 1) * 262144;
      v00 = img[off00];
      v01 = img[off00 + dxs];
      v10 = img[off00 + dys];
      v11 = img[off00 + dys + dxs];
    }
    float w00 = (1.f - cwx) * (1.f - cwy), w01 = cwx * (1.f - cwy);
    float w10 = (1.f - cwx) * cwy, w11 = cwx * cwy;
    float4 val;
    val.x = c00.x * w00 + c01.x * w01 + c10.x * w10 + c11.x * w11;
    val.y = c00.y * w00 + c01.y * w01 + c10.y * w10 + c11.y * w11;
    val.z = c00.z * w00 + c01.z * w01 + c10.z * w10 + c11.z * w11;
    val.w = c00.w * w00 + c01.w * w01 + c10.w * w10 + c11.w * w11;
    if (i == 0) {
      stack = val;
    } else {
      float a = fminf(fmaxf(val.w, 0.0f), 1.0f);
      stack.x = fminf(fmaxf(stack.x - 2.f * a, -1.f), 1.f);
      stack.y = fminf(fmaxf(stack.y - 2.f * a, -1.f), 1.f);
      stack.z = fminf(fmaxf(stack.z - 2.f * a, -1.f), 1.f);
      stack.w = fminf(fmaxf(stack.w - 2.f * a, -1.f), 1.f);
      stack.x = fminf(fmaxf(stack.x + val.x + 1.f, -1.f), 1.f);
      stack.y = fminf(fmaxf(stack.y + val.y + 1.f, -1.f), 1.f);
      stack.z = fminf(fmaxf(stack.z + val.z + 1.f, -1.f), 1.f);
      stack.w = fminf(fmaxf(stack.w + val.w + 1.f, -1.f), 1.f);
    }
  }
  size_t obase = (size_t)b * 4 * 262144 + (size_t)y * 512 + x;
  out[obase] = stack.x;
  out[obase + 262144] = stack.y;
  out[obase + 2 * 262144] = stack.z;
  out[obase + 3 * 262144] = stack.w;
}

extern "C" void kernel_launch(void* const* d_in, const int* in_sizes, int n_in,
                              void* d_out, int out_size, void* d_ws, size_t ws_size,
                              hipStream_t stream) {
  const float4* x4 = (const float4*)d_in[0];
  const float* conv1_w = (const float*)d_in[1];
  const float* conv1_b = (const float*)d_in[2];
  const float* conv2_w = (const float*)d_in[3];
  const float* conv2_b = (const float*)d_in[4];
  const float* fc1_w = (const float*)d_in[5];
  const float* fc1_b = (const float*)d_in[6];
  const float* fc2_w = (const float*)d_in[7];
  const float* fc2_b = (const float*)d_in[8];
  const float* fc3_w = (const float*)d_in[9];
  const float* fc3_b = (const float*)d_in[10];
  float* ws = (float*)d_ws;
  float* out = (float*)d_out;

  conv1_kernel<<<dim3(256, 4), 256, 0, stream>>>(x4, conv1_w, conv1_b, ws + OFF_H1);
  conv2_kernel<<<dim3(64, 4), 256, 0, stream>>>(ws + OFF_H1, conv2_w, conv2_b, ws + OFF_H2);
  fc1_kernel<<<dim3(32, 8), 256, 0, stream>>>(ws + OFF_H2, fc1_w, ws + OFF_PART);
  head_kernel<<<1, 256, 0, stream>>>(ws + OFF_PART, fc1_b, fc2_w, fc2_b, fc3_w, fc3_b,
                                     ws + OFF_THETA, out + 4194304);
  warp_kernel<<<4096, 256, 0, stream>>>(x4, ws + OFF_THETA, out);
}

// Round 13
// 137.103 us; speedup vs baseline: 6.1490x; 6.1490x over previous
//
#include <hip/hip_runtime.h>

#define SS 512
#define NPARTS 11
#define NB 4
#define FEAT (9*126*126)   // 142884

// ws layout (floats)
#define H1SZ (4*7*254*254)       // 1806448
#define H2SZ (4*FEAT)            // 571536
#define OFF_H1 0
#define OFF_H2 (OFF_H1 + H1SZ)
#define OFF_PART (OFF_H2 + H2SZ)      // [32][8][4] = 1024
#define OFF_THETA (OFF_PART + 1024)   // [4][66] = 264

// ---------------- conv1 (5x5, 4->7) + relu + maxpool2 ----------------
// I$-resident body: dy loop NOT unrolled (~5KB). Direct global window reads
// (vmcnt domain, L1). Weights via uniform ds_read_b128 broadcast. NO vgpr cap.
__global__ __launch_bounds__(256) void conv1_kernel(
    const float4* __restrict__ x4,
    const float* __restrict__ w,      // [7][4][5][5] original layout
    const float* __restrict__ bias,   // [7]
    float* __restrict__ h1) {
  __shared__ float4 wlds[175];        // [tap 25][k 7], float4 over c (2.8 KB)
  int tid = threadIdx.x;
  {
    float* wf = (float*)wlds;
    for (int i = tid; i < 700; i += 256) {
      int tap = i / 28, r = i % 28;
      int k = r >> 2, c = r & 3;
      int dy = tap / 5, dx = tap % 5;
      wf[i] = w[((k * 4 + c) * 5 + dy) * 5 + dx];
    }
  }
  __syncthreads();

  int b = blockIdx.y;
  int by = blockIdx.x >> 4, bx = blockIdx.x & 15;
  int ty = tid >> 4, tx = tid & 15;
  int py = by * 16 + ty, px = bx * 16 + tx;
  if (py >= 254 || px >= 254) return;   // after barrier: safe

  const float4* img = x4 + (size_t)b * 6144 * 512 + (size_t)(2 * py) * 512 + 2 * px;

  float acc[4][7];
#pragma unroll
  for (int p = 0; p < 4; p++)
#pragma unroll
    for (int k = 0; k < 7; k++) acc[p][k] = bias[k];

#pragma unroll 1
  for (int dy = 0; dy < 5; dy++) {
    const float4* r0 = img + dy * 512;
    const float4* r1 = r0 + 512;
    float4 a0[6], a1[6];
#pragma unroll
    for (int j = 0; j < 6; j++) { a0[j] = r0[j]; a1[j] = r1[j]; }
#pragma unroll
    for (int dx = 0; dx < 5; dx++) {
      float4 v00 = a0[dx], v01 = a0[dx + 1];
      float4 v10 = a1[dx], v11 = a1[dx + 1];
      const float4* wp = &wlds[(dy * 5 + dx) * 7];
#pragma unroll
      for (int k = 0; k < 7; k++) {
        float4 wv = wp[k];                 // uniform ds_read_b128 broadcast
        acc[0][k] += v00.x * wv.x + v00.y * wv.y + v00.z * wv.z + v00.w * wv.w;
        acc[1][k] += v01.x * wv.x + v01.y * wv.y + v01.z * wv.z + v01.w * wv.w;
        acc[2][k] += v10.x * wv.x + v10.y * wv.y + v10.z * wv.z + v10.w * wv.w;
        acc[3][k] += v11.x * wv.x + v11.y * wv.y + v11.z * wv.z + v11.w * wv.w;
      }
    }
  }

#pragma unroll
  for (int k = 0; k < 7; k++) {
    float m = fmaxf(fmaxf(acc[0][k], acc[1][k]), fmaxf(acc[2][k], acc[3][k]));
    h1[(((size_t)b * 7 + k) * 254 + py) * 254 + px] = fmaxf(m, 0.0f);
  }
}

// ---------------- conv2 (3x3, 7->9) + relu + maxpool2, LDS-tiled ----------------
__global__ __launch_bounds__(256) void conv2_kernel(
    const float* __restrict__ h1,     // [4][7][254][254]
    const float* __restrict__ w,      // [9][7][3][3]
    const float* __restrict__ bias,   // [9]
    float* __restrict__ h2) {
  __shared__ float tile[7 * 34 * 35];
  int tid = threadIdx.x;
  int b = blockIdx.y;
  int by = blockIdx.x >> 3, bx = blockIdx.x & 7;
  int y0 = by * 32, x0 = bx * 32;

  for (int i = tid; i < 7 * 34 * 34; i += 256) {
    int c = i / (34 * 34), rem = i % (34 * 34);
    int r = rem / 34, col = rem % 34;
    int gy = y0 + r, gx = x0 + col;
    float v = 0.f;
    if (gy < 254 && gx < 254)
      v = h1[(((size_t)b * 7 + c) * 254 + gy) * 254 + gx];
    tile[(c * 34 + r) * 35 + col] = v;
  }
  __syncthreads();

  int ty = tid >> 4, tx = tid & 15;
  float acc[4][9];
#pragma unroll
  for (int p = 0; p < 4; p++)
#pragma unroll
    for (int k = 0; k < 9; k++) acc[p][k] = bias[k];

  for (int c = 0; c < 7; c++) {
#pragma unroll
    for (int dy = 0; dy < 3; dy++) {
      const float* r0 = &tile[(c * 34 + 2 * ty + dy) * 35 + 2 * tx];
      const float* r1 = r0 + 35;
      float a0[4], a1[4];
#pragma unroll
      for (int j = 0; j < 4; j++) { a0[j] = r0[j]; a1[j] = r1[j]; }
#pragma unroll
      for (int dx = 0; dx < 3; dx++) {
#pragma unroll
        for (int k = 0; k < 9; k++) {
          float wv = w[k * 63 + c * 9 + dy * 3 + dx];  // uniform -> scalar load
          acc[0][k] += a0[dx] * wv;
          acc[1][k] += a0[dx + 1] * wv;
          acc[2][k] += a1[dx] * wv;
          acc[3][k] += a1[dx + 1] * wv;
        }
      }
    }
  }

  int py = by * 16 + ty, px = bx * 16 + tx;
  if (py < 126 && px < 126) {
#pragma unroll
    for (int k = 0; k < 9; k++) {
      float m = fmaxf(fmaxf(acc[0][k], acc[1][k]), fmaxf(acc[2][k], acc[3][k]));
      h2[(((size_t)b * 9 + k) * 126 + py) * 126 + px] = fmaxf(m, 0.0f);
    }
  }
}

// ---------------- fc1 split-K partials ----------------
__global__ __launch_bounds__(256) void fc1_kernel(
    const float* __restrict__ h2,    // [4][FEAT]
    const float* __restrict__ w,     // [32][FEAT]
    float* __restrict__ partials) {
  int j = blockIdx.x;
  int s = blockIdx.y;
  int tid = threadIdx.x;
  const int CH = (FEAT + 7) / 8;
  int f0 = s * CH;
  int f1 = f0 + CH; if (f1 > FEAT) f1 = FEAT;
  float a0 = 0.f, a1 = 0.f, a2 = 0.f, a3 = 0.f;
  const float* wj = w + (size_t)j * FEAT;
  for (int f = f0 + tid; f < f1; f += 256) {
    float wv = wj[f];
    a0 += wv * h2[f];
    a1 += wv * h2[FEAT + f];
    a2 += wv * h2[2 * FEAT + f];
    a3 += wv * h2[3 * FEAT + f];
  }
  __shared__ float4 red[256];
  red[tid] = make_float4(a0, a1, a2, a3);
  __syncthreads();
  for (int off = 128; off > 0; off >>= 1) {
    if (tid < off) {
      float4 o = red[tid + off];
      red[tid].x += o.x; red[tid].y += o.y; red[tid].z += o.z; red[tid].w += o.w;
    }
    __syncthreads();
  }
  if (tid == 0) {
    float4 r = red[0];
    float* p = partials + ((size_t)j * 8 + s) * 4;
    p[0] = r.x; p[1] = r.y; p[2] = r.z; p[3] = r.w;
  }
}

// ---------------- head: finish fc1, fc2, fc3, side outputs ----------------
__global__ __launch_bounds__(256) void head_kernel(
    const float* __restrict__ partials,
    const float* __restrict__ b1,     // [32]
    const float* __restrict__ w2,     // [33][32]
    const float* __restrict__ b2,     // [33]
    const float* __restrict__ w3,     // [66][33]
    const float* __restrict__ b3,     // [66]
    float* __restrict__ theta_out,    // [4][66]
    float* __restrict__ out_tail) {   // close_to_eye(176) + translations(88)
  __shared__ float h32[128];
  __shared__ float h33[132];
  __shared__ float th[264];
  int tid = threadIdx.x;
  for (int t = tid; t < 128; t += 256) {
    int b = t >> 5, j = t & 31;
    float sacc = b1[j];
    for (int k = 0; k < 8; k++) sacc += partials[((size_t)j * 8 + k) * 4 + b];
    h32[b * 32 + j] = fmaxf(sacc, 0.0f);
  }
  __syncthreads();
  for (int t = tid; t < 132; t += 256) {
    int b = t / 33, j2 = t % 33;
    float sacc = b2[j2];
    for (int j = 0; j < 32; j++) sacc += h32[b * 32 + j] * w2[j2 * 32 + j];
    h33[b * 33 + j2] = fmaxf(sacc, 0.0f);
  }
  __syncthreads();
  for (int t = tid; t < 264; t += 256) {
    int b = t / 66, u = t % 66;
    float sacc = b3[u];
    for (int j2 = 0; j2 < 33; j2++) sacc += h33[b * 33 + j2] * w3[u * 33 + j2];
    th[t] = sacc;
    theta_out[t] = sacc;
  }
  __syncthreads();
  for (int t = tid; t < 176; t += 256) {
    int b = t / 44, r = t % 44, p = r / 4, ik = r % 4;
    int i = ik >> 1, k = ik & 1;
    const float* T = &th[b * 66 + p * 6];
    out_tail[t] = T[i * 3 + 0] * T[k * 3 + 0] + T[i * 3 + 1] * T[k * 3 + 1];
  }
  for (int t = tid; t < 88; t += 256) {
    int b = t / 22, r = t % 22, p = r / 2, i = r % 2;
    out_tail[176 + t] = th[b * 66 + p * 6 + i * 3 + 2];
  }
}

// ---------------- warp + alpha composite, depth-2 cross-part pipeline ----------------
__global__ __launch_bounds__(256) void warp_kernel(
    const float4* __restrict__ x4,
    const float* __restrict__ theta,  // [4][66]
    float* __restrict__ out) {
  int bid = blockIdx.x;
  int swz = (bid & 7) * 512 + (bid >> 3);   // 4096 blocks, XCD-chunked
  int b = swz >> 10;
  int t = swz & 1023;
  int ty = t >> 5, tx = t & 31;             // 32x32 tiles of 16x16
  int tid = threadIdx.x;
  int wv = tid >> 6, l = tid & 63;
  int y = ty * 16 + wv * 4 + (l >> 4);
  int x = tx * 16 + (l & 15);

  __shared__ float th[66];
  if (tid < 66) th[tid] = theta[b * 66 + tid];
  __syncthreads();

  const float4* img0 = x4 + (size_t)b * 6144 * 512 + 262144;  // part 0 chunk
  float fx = (float)x, fy = (float)y;
  const float cn = (1.0f / 512.0f) - 1.0f;

  float4 v00, v01, v10, v11;
  float wx, wy;
  {
    float T0 = th[0], T1 = th[1], T2 = th[2];
    float T3 = th[3], T4 = th[4], T5 = th[5];
    float Cx = 256.0f * ((T0 + T1) * cn + T2) + 255.5f;
    float Cy = 256.0f * ((T3 + T4) * cn + T5) + 255.5f;
    float ix = fmaf(T0, fx, fmaf(T1, fy, Cx));
    float iy = fmaf(T3, fx, fmaf(T4, fy, Cy));
    float xf = floorf(ix), yf = floorf(iy);
    wx = ix - xf; wy = iy - yf;
    int x0i = min(max((int)xf, 0), 511);
    int x1i = min(max((int)xf + 1, 0), 511);
    int y0i = min(max((int)yf, 0), 511);
    int y1i = min(max((int)yf + 1, 0), 511);
    int off00 = y0i * 512 + x0i;
    int dxs = x1i - x0i, dys = (y1i - y0i) * 512;
    v00 = img0[off00];
    v01 = img0[off00 + dxs];
    v10 = img0[off00 + dys];
    v11 = img0[off00 + dys + dxs];
  }

  float4 stack = make_float4(0.f, 0.f, 0.f, 0.f);
#pragma unroll 1
  for (int i = 0; i < NPARTS; i++) {
    float cwx = wx, cwy = wy;
    float4 c00 = v00, c01 = v01, c10 = v10, c11 = v11;
    if (i + 1 < NPARTS) {
      float T0 = th[(i + 1) * 6 + 0], T1 = th[(i + 1) * 6 + 1], T2 = th[(i + 1) * 6 + 2];
      float T3 = th[(i + 1) * 6 + 3], T4 = th[(i + 1) * 6 + 4], T5 = th[(i + 1) * 6 + 5];
      float Cx = 256.0f * ((T0 + T1) * cn + T2) + 255.5f;
      float Cy = 256.0f * ((T3 + T4) * cn + T5) + 255.5f;
      float ix = fmaf(T0, fx, fmaf(T1, fy, Cx));
      float iy = fmaf(T3, fx, fmaf(T4, fy, Cy));
      float xf = floorf(ix), yf = floorf(iy);
      wx = ix - xf; wy = iy - yf;
      int x0i = min(max((int)xf, 0), 511);
      int x1i = min(max((int)xf + 1, 0), 511);
      int y0i = min(max((int)yf, 0), 511);
      int y1i = min(max((int)yf + 1, 0), 511);
      int off00 = y0i * 512 + x0i;
      int dxs = x1i - x0i, dys = (y1i - y0i) * 512;
      const float4* img = img0 + (size_t)(i + 1) * 262144;
      v00 = img[off00];
      v01 = img[off00 + dxs];
      v10 = img[off00 + dys];
      v11 = img[off00 + dys + dxs];
    }
    float w00 = (1.f - cwx) * (1.f - cwy), w01 = cwx * (1.f - cwy);
    float w10 = (1.f - cwx) * cwy, w11 = cwx * cwy;
    float4 val;
    val.x = c00.x * w00 + c01.x * w01 + c10.x * w10 + c11.x * w11;
    val.y = c00.y * w00 + c01.y * w01 + c10.y * w10 + c11.y * w11;
    val.z = c00.z * w00 + c01.z * w01 + c10.z * w10 + c11.z * w11;
    val.w = c00.w * w00 + c01.w * w01 + c10.w * w10 + c11.w * w11;
    if (i == 0) {
      stack = val;
    } else {
      float a = fminf(fmaxf(val.w, 0.0f), 1.0f);
      stack.x = fminf(fmaxf(stack.x - 2.f * a, -1.f), 1.f);
      stack.y = fminf(fmaxf(stack.y - 2.f * a, -1.f), 1.f);
      stack.z = fminf(fmaxf(stack.z - 2.f * a, -1.f), 1.f);
      stack.w = fminf(fmaxf(stack.w - 2.f * a, -1.f), 1.f);
      stack.x = fminf(fmaxf(stack.x + val.x + 1.f, -1.f), 1.f);
      stack.y = fminf(fmaxf(stack.y + val.y + 1.f, -1.f), 1.f);
      stack.z = fminf(fmaxf(stack.z + val.z + 1.f, -1.f), 1.f);
      stack.w = fminf(fmaxf(stack.w + val.w + 1.f, -1.f), 1.f);
    }
  }
  size_t obase = (size_t)b * 4 * 262144 + (size_t)y * 512 + x;
  out[obase] = stack.x;
  out[obase + 262144] = stack.y;
  out[obase + 2 * 262144] = stack.z;
  out[obase + 3 * 262144] = stack.w;
}

extern "C" void kernel_launch(void* const* d_in, const int* in_sizes, int n_in,
                              void* d_out, int out_size, void* d_ws, size_t ws_size,
                              hipStream_t stream) {
  const float4* x4 = (const float4*)d_in[0];
  const float* conv1_w = (const float*)d_in[1];
  const float* conv1_b = (const float*)d_in[2];
  const float* conv2_w = (const float*)d_in[3];
  const float* conv2_b = (const float*)d_in[4];
  const float* fc1_w = (const float*)d_in[5];
  const float* fc1_b = (const float*)d_in[6];
  const float* fc2_w = (const float*)d_in[7];
  const float* fc2_b = (const float*)d_in[8];
  const float* fc3_w = (const float*)d_in[9];
  const float* fc3_b = (const float*)d_in[10];
  float* ws = (float*)d_ws;
  float* out = (float*)d_out;

  conv1_kernel<<<dim3(256, 4), 256, 0, stream>>>(x4, conv1_w, conv1_b, ws + OFF_H1);
  conv2_kernel<<<dim3(64, 4), 256, 0, stream>>>(ws + OFF_H1, conv2_w, conv2_b, ws + OFF_H2);
  fc1_kernel<<<dim3(32, 8), 256, 0, stream>>>(ws + OFF_H2, fc1_w, ws + OFF_PART);
  head_kernel<<<1, 256, 0, stream>>>(ws + OFF_PART, fc1_b, fc2_w, fc2_b, fc3_w, fc3_b,
                                     ws + OFF_THETA, out + 4194304);
  warp_kernel<<<4096, 256, 0, stream>>>(x4, ws + OFF_THETA, out);
}